// Round 1
// baseline (110.682 us; speedup 1.0000x reference)
//
#include <hip/hip_runtime.h>

// Problem constants (match reference: S, B, D, MAX_LEN, P = 4096, 64, 256, 4096, 8)
#define S_LEN 4096
#define BATCH 64
#define DIM 256
#define NPEAK 8

// Kernel 1: out[s,b,d] = x[s,b,d] + pe[s,d]   (pe broadcast over batch)
// float4-vectorized grid-stride loop. total4 = S*B*D/4 float4 elements.
__global__ void pe_add_kernel(const float4* __restrict__ x,
                              const float4* __restrict__ pe,
                              float4* __restrict__ out,
                              int total4) {
    int tid = blockIdx.x * blockDim.x + threadIdx.x;
    int stride = gridDim.x * blockDim.x;
    const int row4 = BATCH * DIM / 4;  // float4 per seq position (all batches)
    const int d4n = DIM / 4;           // float4 per dim row
    for (int i = tid; i < total4; i += stride) {
        int s = i / row4;        // seq position
        int d4 = i % d4n;        // float4 index within dim (flat%D)/4 == i % (D/4)
        float4 xv = x[i];
        float4 pv = pe[s * d4n + d4];
        float4 o;
        o.x = xv.x + pv.x;
        o.y = xv.y + pv.y;
        o.z = xv.z + pv.z;
        o.w = xv.w + pv.w;
        out[i] = o;
    }
}

// Kernel 2: for each (b,p) peak, atomically add table[peak][:] into out[peak, b, :].
// 512 blocks x 256 threads; duplicates accumulate via atomics (device-scope by default).
__global__ void peak_scatter_kernel(const int* __restrict__ peaks,
                                    const float* __restrict__ table,
                                    float* __restrict__ out) {
    int bp = blockIdx.x;          // 0 .. B*P-1
    int b = bp / NPEAK;
    int p = peaks[bp];
    if (p < 0 || p >= S_LEN) return;  // invalid peaks contribute zero
    int d = threadIdx.x;              // DIM == blockDim.x == 256
    size_t off = (size_t)p * (BATCH * DIM) + (size_t)b * DIM + d;
    atomicAdd(&out[off], table[(size_t)p * DIM + d]);
}

extern "C" void kernel_launch(void* const* d_in, const int* in_sizes, int n_in,
                              void* d_out, int out_size, void* d_ws, size_t ws_size,
                              hipStream_t stream) {
    const float* x     = (const float*)d_in[0];   // [S, B, D] f32
    const int* peaks   = (const int*)d_in[1];     // [B, P] i32
    const float* pe    = (const float*)d_in[2];   // [MAX_LEN, 1, D] f32
    const float* table = (const float*)d_in[3];   // [MAX_LEN, D] f32
    float* out = (float*)d_out;                   // [S, B, D] f32

    const int total4 = S_LEN * BATCH * DIM / 4;   // 16,777,216 float4
    const int block = 256;
    int grid = (total4 + block - 1) / block;
    if (grid > 2048) grid = 2048;                 // grid-stride the rest (G11)

    pe_add_kernel<<<grid, block, 0, stream>>>(
        (const float4*)x, (const float4*)pe, (float4*)out, total4);

    peak_scatter_kernel<<<BATCH * NPEAK, DIM, 0, stream>>>(peaks, table, out);
}

// Round 2
// 104.068 us; speedup vs baseline: 1.0636x; 1.0636x over previous
//
#include <hip/hip_runtime.h>

// Problem constants (reference: S, B, D, MAX_LEN, P = 4096, 64, 256, 4096, 8)
#define S_LEN 4096
#define BATCH 64
#define DIM 256
#define NPEAK 8
#define TOTAL4 (S_LEN * BATCH * DIM / 4)  // 16,777,216 float4 elements

typedef float f32x4 __attribute__((ext_vector_type(4)));

// Fused: out[s,b,d] = x[s,b,d] + pe[s,d] + count(s,b) * table[s,d]
// where count(s,b) = #{ j : peaks[b,j] == s } (duplicates accumulate; invalid
// peaks never match an s in [0,S) so they contribute zero — matches reference).
//
// Wave-level structure: lane = d4 (64 float4 per D-row), so (s,b) is uniform
// per wave -> no divergence on the cnt branch, peak compares are effectively
// scalar. With stride = 2^19 (grid 2048 x block 256), b and d4 are invariant
// across grid-stride iterations -> hoist the 8 peak loads out of the loop.
__global__ __launch_bounds__(256) void fused_pe_peak_kernel(
    const f32x4* __restrict__ x,
    const int*   __restrict__ peaks,
    const f32x4* __restrict__ pe,
    const f32x4* __restrict__ table,
    f32x4* __restrict__ out)
{
    const int tid = blockIdx.x * blockDim.x + threadIdx.x;
    const int stride = gridDim.x * blockDim.x;   // 2^19; (stride>>6) % 64 == 0
    const int b  = (tid >> 6) & (BATCH - 1);     // invariant across iterations
    const int d4 = tid & (DIM / 4 - 1);          // invariant across iterations

    int pk[NPEAK];
    #pragma unroll
    for (int j = 0; j < NPEAK; ++j) pk[j] = peaks[b * NPEAK + j];

    for (int i = tid; i < TOTAL4; i += stride) {
        const int s = i >> 12;                   // i / (BATCH*DIM/4)
        f32x4 xv = __builtin_nontemporal_load(&x[i]);   // streamed, no reuse
        f32x4 pv = pe[(s << 6) + d4];                   // 4 MB, L2-resident
        f32x4 o = xv + pv;

        int cnt = 0;
        #pragma unroll
        for (int j = 0; j < NPEAK; ++j) cnt += (pk[j] == s) ? 1 : 0;
        if (cnt) {                               // wave-uniform; true ~0.2% of rows
            f32x4 tv = table[(s << 6) + d4];
            o += (float)cnt * tv;
        }
        __builtin_nontemporal_store(o, &out[i]); // streamed, written once
    }
}

extern "C" void kernel_launch(void* const* d_in, const int* in_sizes, int n_in,
                              void* d_out, int out_size, void* d_ws, size_t ws_size,
                              hipStream_t stream) {
    const float* x     = (const float*)d_in[0];   // [S, B, D] f32
    const int* peaks   = (const int*)d_in[1];     // [B, P] i32
    const float* pe    = (const float*)d_in[2];   // [MAX_LEN, 1, D] f32
    const float* table = (const float*)d_in[3];   // [MAX_LEN, D] f32

    // grid*block = 2^19 exactly: required for the b/d4 hoisting invariant.
    fused_pe_peak_kernel<<<2048, 256, 0, stream>>>(
        (const f32x4*)x, peaks, (const f32x4*)pe, (const f32x4*)table,
        (f32x4*)d_out);
}